// Round 14
// baseline (777.364 us; speedup 1.0000x reference)
//
#include <hip/hip_runtime.h>
#include <hip/hip_bf16.h>
#include <math.h>

typedef __attribute__((ext_vector_type(8))) short short8;
typedef __attribute__((ext_vector_type(4))) short sv4;
typedef __attribute__((ext_vector_type(4))) float f32x4;
typedef unsigned int u32;

#define BT_ 384
#define N_ 716
#define C_ 256
#define H_ 8
#define D_ 32
#define MROWS (BT_ * N_)   /* 274944 */
#define NT_ (MROWS / 64)   /* 4296 row-tiles of 64 */
#define SCALE_ 0.17677669529663687f  /* 32^-0.5 */
#define INVN_ (1.0f / 716.0f)

__device__ __forceinline__ void gload_lds16(const void* g, void* l) {
    __builtin_amdgcn_global_load_lds(
        (const __attribute__((address_space(1))) u32*)g,
        (__attribute__((address_space(3))) u32*)l, 16, 0, 0);
}

// ---------------------------------------------------------------------------
// Assemble bf16 weight matrices + fused qkv bias. Wqkv_b[768][256], Wo_b[256][256]
// ---------------------------------------------------------------------------
__global__ void prep_weights(const float* __restrict__ Wq, const float* __restrict__ bq,
                             const float* __restrict__ Wk, const float* __restrict__ bk,
                             const float* __restrict__ Wv, const float* __restrict__ bv,
                             const float* __restrict__ Wo,
                             __hip_bfloat16* __restrict__ wqkv, float* __restrict__ bqkv,
                             __hip_bfloat16* __restrict__ wo) {
    int idx = blockIdx.x * 256 + threadIdx.x;
    if (idx < 768 * 256) {
        int o = idx >> 8, c = idx & 255;
        const float* W = (o < 256) ? Wq : ((o < 512) ? Wk : Wv);
        int oo = o & 255;
        wqkv[idx] = __float2bfloat16(W[oo * 256 + c]);
    }
    if (idx < 256 * 256) wo[idx] = __float2bfloat16(Wo[idx]);
    if (idx < 768) bqkv[idx] = (idx < 256) ? bq[idx] : ((idx < 512) ? bk[idx - 256] : bv[idx - 512]);
}

// ---------------------------------------------------------------------------
// Grouped 2-layer MLP -> per-channel 3-tap conv weights rw[bt][768]
// ---------------------------------------------------------------------------
__global__ __launch_bounds__(256)
void mlp_rw(const float* __restrict__ msum, const float* __restrict__ w1,
            const float* __restrict__ b1, const float* __restrict__ w2,
            const float* __restrict__ b2, float* __restrict__ rw) {
    int bt = blockIdx.x;
    int t = threadIdx.x;
    __shared__ float m_l[256];
    __shared__ float h1_l[256];
    m_l[t] = msum[bt * 256 + t] * INVN_;
    __syncthreads();
    int g = t >> 5;
    float a = b1[t];
    #pragma unroll
    for (int i = 0; i < 32; ++i) a += m_l[g * 32 + i] * w1[t * 32 + i];
    h1_l[t] = 0.5f * a * (1.0f + erff(a * 0.70710678118654752f));
    __syncthreads();
    for (int o = t; o < 768; o += 256) {
        int gg = o / 96;
        float s = b2[o];
        #pragma unroll
        for (int i = 0; i < 32; ++i) s += h1_l[gg * 32 + i] * w2[o * 32 + i];
        rw[bt * 768 + o] = s;
    }
}

// ---------------------------------------------------------------------------
// gemm_xfused: QKV projection reading x (f32) DIRECTLY. R9 gemm structure
// (4 waves, wave=64x32, dbuf 2x32KB, B in regs, XCD grid, stage-before-
// compute) with reg-staged A: 16 float4 loads -> f32->bf16 convert ->
// 8 ds_write_b128 (XOR swizzle matching the read side). cb==0 blocks also
// accumulate msum (per-bt channel sums of x) from the f32 registers.
// grid 1536 (1D), block 256.
// ---------------------------------------------------------------------------
__global__ __launch_bounds__(256, 2)
void gemm_xfused(const float* __restrict__ X, const __hip_bfloat16* __restrict__ Bm,
                 const float* __restrict__ bias, __hip_bfloat16* __restrict__ qkv,
                 float* __restrict__ msum) {
    __shared__ __align__(16) __hip_bfloat16 As[2][64 * 256];   // 2 x 32KB
    const int L = blockIdx.x;
    const int xcd = L & 7, w = L >> 3;
    const int cb = w % 6;
    const int ib = xcd * 32 + w / 6;        // stripe 0..255
    const int tid = threadIdx.x;
    const int lane = tid & 63;
    const int wave = tid >> 6;              // 0..3
    const int wn = wave;                    // 32-col quarter
    const int colBase = cb * 128;
    const int l15 = lane & 15, lq = lane >> 4;
    const int slot = tid & 31;              // 16B slot within 512B row
    const int rowg = tid >> 5;              // 0..7 row group
    const bool domsum = (cb == 0);

    float4 fA[8], fB[8];                    // staged x rows: rowg+8j, 8 f32 each

    auto loadX = [&](int rt) {
        #pragma unroll
        for (int j = 0; j < 8; ++j) {
            size_t row = (size_t)rt * 64 + rowg + 8 * j;
            fA[j] = *(const float4*)&X[row * 256 + slot * 8];
            fB[j] = *(const float4*)&X[row * 256 + slot * 8 + 4];
        }
    };
    auto stageX = [&](int buf, int rt) {
        float s0[8], s1[8];
        int bt0 = 0, rb = 64;
        if (domsum) {
            int base = rt * 64;
            bt0 = base / N_;
            rb = (bt0 + 1) * N_ - base;     // rows >= rb belong to bt0+1
            #pragma unroll
            for (int jj = 0; jj < 8; ++jj) { s0[jj] = 0.f; s1[jj] = 0.f; }
        }
        #pragma unroll
        for (int j = 0; j < 8; ++j) {
            int r = rowg + 8 * j;
            union { short8 v; __hip_bfloat16 h[8]; } u;
            u.h[0] = __float2bfloat16(fA[j].x); u.h[1] = __float2bfloat16(fA[j].y);
            u.h[2] = __float2bfloat16(fA[j].z); u.h[3] = __float2bfloat16(fA[j].w);
            u.h[4] = __float2bfloat16(fB[j].x); u.h[5] = __float2bfloat16(fB[j].y);
            u.h[6] = __float2bfloat16(fB[j].z); u.h[7] = __float2bfloat16(fB[j].w);
            *(short8*)&As[buf][r * 256 + ((slot ^ (r & 7)) * 8)] = u.v;
            if (domsum) {
                float in0 = (r < rb) ? 1.0f : 0.0f, in1 = 1.0f - in0;
                s0[0] += fA[j].x * in0; s1[0] += fA[j].x * in1;
                s0[1] += fA[j].y * in0; s1[1] += fA[j].y * in1;
                s0[2] += fA[j].z * in0; s1[2] += fA[j].z * in1;
                s0[3] += fA[j].w * in0; s1[3] += fA[j].w * in1;
                s0[4] += fB[j].x * in0; s1[4] += fB[j].x * in1;
                s0[5] += fB[j].y * in0; s1[5] += fB[j].y * in1;
                s0[6] += fB[j].z * in0; s1[6] += fB[j].z * in1;
                s0[7] += fB[j].w * in0; s1[7] += fB[j].w * in1;
            }
        }
        if (domsum) {
            #pragma unroll
            for (int jj = 0; jj < 8; ++jj)
                atomicAdd(&msum[bt0 * 256 + slot * 8 + jj], s0[jj]);
            if (rb < 64) {
                #pragma unroll
                for (int jj = 0; jj < 8; ++jj)
                    atomicAdd(&msum[(bt0 + 1) * 256 + slot * 8 + jj], s1[jj]);
            }
        }
    };

    // B fragments in registers (loop-invariant, L2-hot weights)
    short8 bf[2][8];
    #pragma unroll
    for (int n = 0; n < 2; ++n)
        #pragma unroll
        for (int ks = 0; ks < 8; ++ks)
            bf[n][ks] = *(const short8*)&Bm[(size_t)(colBase + wn * 32 + n * 16 + l15) * 256 + ks * 32 + lq * 8];
    float biasr[2];
    #pragma unroll
    for (int n = 0; n < 2; ++n)
        biasr[n] = bias[colBase + wn * 32 + n * 16 + l15];

    // prologue: tile0 staged into buf0; tile1 loads in flight
    loadX(ib);
    stageX(0, ib);
    if (ib + 256 < NT_) loadX(ib + 256);
    asm volatile("s_waitcnt lgkmcnt(0)" ::: "memory");
    __builtin_amdgcn_s_barrier();

    int buf = 0;
    for (int rt = ib; rt < NT_; rt += 256) {
        if (rt + 256 < NT_) stageX(buf ^ 1, rt + 256);   // ds_write tile t+1 (regs ready)
        if (rt + 512 < NT_) loadX(rt + 512);             // issue loads for t+2

        // ---- compute 64x128 from As[buf], B in regs ----
        f32x4 acc[4][2] = {};
        #pragma unroll
        for (int ks = 0; ks < 8; ++ks) {
            short8 af[4];
            #pragma unroll
            for (int m = 0; m < 4; ++m) {
                int row = m * 16 + l15;
                af[m] = *(const short8*)&As[buf][row * 256 + (((ks * 4 + lq) ^ (row & 7)) * 8)];
            }
            #pragma unroll
            for (int m = 0; m < 4; ++m)
                #pragma unroll
                for (int n = 0; n < 2; ++n)
                    acc[m][n] = __builtin_amdgcn_mfma_f32_16x16x32_bf16(af[m], bf[n][ks], acc[m][n], 0, 0, 0);
        }
        asm volatile("s_waitcnt lgkmcnt(0)" ::: "memory");
        __builtin_amdgcn_s_barrier();        // reads of As[buf] + stage writes done

        // ---- epilogue: Cs in dead As[buf], coalesced short8 stores ----
        __hip_bfloat16* Cs = &As[buf][0];    // [64][136]
        #pragma unroll
        for (int m = 0; m < 4; ++m)
            #pragma unroll
            for (int n = 0; n < 2; ++n) {
                int col = wn * 32 + n * 16 + l15;
                #pragma unroll
                for (int j = 0; j < 4; ++j)
                    Cs[(m * 16 + lq * 4 + j) * 136 + col] =
                        __float2bfloat16(acc[m][n][j] + biasr[n]);
            }
        asm volatile("s_waitcnt lgkmcnt(0)" ::: "memory");
        __builtin_amdgcn_s_barrier();
        {
            int row = tid >> 2, cq = tid & 3;
            __hip_bfloat16* og = qkv + ((size_t)rt * 64 + row) * 768 + colBase;
            #pragma unroll
            for (int i = 0; i < 4; ++i) {
                int col = cq * 8 + i * 32;
                *(short8*)&og[col] = *(const short8*)&Cs[row * 136 + col];
            }
        }
        asm volatile("s_waitcnt lgkmcnt(0)" ::: "memory");
        __builtin_amdgcn_s_barrier();
        buf ^= 1;
    }
}

// ---------------------------------------------------------------------------
// gemm_out: R9 gemm_persist verbatim (<256, GRIDX=2, f32 out). 4 waves,
// wave 64x32, dbuf, gload_lds, B in regs, XCD grid, stage-before-compute,
// two-pass padded f32 epilogue, counted vmcnt at tile end.
// ---------------------------------------------------------------------------
__global__ __launch_bounds__(256, 2)
void gemm_out(const __hip_bfloat16* __restrict__ A, const __hip_bfloat16* __restrict__ Bm,
              const float* __restrict__ bias, float* __restrict__ outp) {
    __shared__ __align__(16) __hip_bfloat16 As[2][64 * 256];   // 2 x 32KB
    constexpr int GRIDX = 2, NCOLS = 256;
    const int L = blockIdx.x;
    const int xcd = L & 7, w = L >> 3;
    const int cb = w % GRIDX;
    const int ib = xcd * 32 + w / GRIDX;
    const int tid = threadIdx.x;
    const int lane = tid & 63;
    const int wave = tid >> 6;
    const int wn = wave;
    const int colBase = cb * 128;
    const int l15 = lane & 15, lq = lane >> 4;
    const int lrow2 = lane >> 5;
    const int p = lane & 31;

    auto stageA = [&](int rt, int buf) {
        #pragma unroll
        for (int i = 0; i < 8; ++i) {
            int r = wave * 16 + 2 * i + lrow2;
            const __hip_bfloat16* g = A + ((size_t)rt * 64 + r) * 256 + ((p ^ (r & 7)) * 8);
            gload_lds16(g, &As[buf][(wave * 16 + 2 * i) * 256]);
        }
    };

    stageA(ib, 0);

    short8 bf[2][8];
    #pragma unroll
    for (int n = 0; n < 2; ++n)
        #pragma unroll
        for (int ks = 0; ks < 8; ++ks)
            bf[n][ks] = *(const short8*)&Bm[(size_t)(colBase + wn * 32 + n * 16 + l15) * 256 + ks * 32 + lq * 8];
    float biasr[2];
    #pragma unroll
    for (int n = 0; n < 2; ++n)
        biasr[n] = bias[colBase + wn * 32 + n * 16 + l15];

    asm volatile("s_waitcnt vmcnt(0)" ::: "memory");
    __builtin_amdgcn_s_barrier();

    int buf = 0;
    for (int rt = ib; rt < NT_; rt += 256) {
        int rtn = rt + 256;
        if (rtn < NT_) stageA(rtn, buf ^ 1);

        f32x4 acc[4][2] = {};
        #pragma unroll
        for (int ks = 0; ks < 8; ++ks) {
            short8 af[4];
            #pragma unroll
            for (int m = 0; m < 4; ++m) {
                int row = m * 16 + l15;
                af[m] = *(const short8*)&As[buf][row * 256 + (((ks * 4 + lq) ^ (row & 7)) * 8)];
            }
            #pragma unroll
            for (int m = 0; m < 4; ++m)
                #pragma unroll
                for (int n = 0; n < 2; ++n)
                    acc[m][n] = __builtin_amdgcn_mfma_f32_16x16x32_bf16(af[m], bf[n][ks], acc[m][n], 0, 0, 0);
        }
        asm volatile("s_waitcnt lgkmcnt(0)" ::: "memory");
        __builtin_amdgcn_s_barrier();

        float* Cs = (float*)&As[buf][0];   // [32][132] per pass
        #pragma unroll
        for (int pp = 0; pp < 2; ++pp) {
            #pragma unroll
            for (int mm = 0; mm < 2; ++mm) {
                int m = 2 * pp + mm;
                #pragma unroll
                for (int n = 0; n < 2; ++n) {
                    int col = wn * 32 + n * 16 + l15;
                    #pragma unroll
                    for (int j = 0; j < 4; ++j)
                        Cs[(mm * 16 + lq * 4 + j) * 132 + col] = acc[m][n][j] + biasr[n];
                }
            }
            asm volatile("s_waitcnt lgkmcnt(0)" ::: "memory");
            __builtin_amdgcn_s_barrier();
            int row = tid >> 3, k = tid & 7;
            float* og = outp + ((size_t)rt * 64 + pp * 32 + row) * NCOLS + colBase;
            #pragma unroll
            for (int i = 0; i < 4; ++i) {
                int col = k * 4 + i * 32;
                *(float4*)&og[col] = *(const float4*)&Cs[row * 132 + col];
            }
            asm volatile("s_waitcnt lgkmcnt(0)" ::: "memory");
            __builtin_amdgcn_s_barrier();
        }
        asm volatile("s_waitcnt vmcnt(4) lgkmcnt(0)" ::: "memory");
        __builtin_amdgcn_s_barrier();
        buf ^= 1;
    }
}

// ---------------------------------------------------------------------------
// MFMA reduce_kv (unchanged): one block per bt, 8 waves = 8 heads.
// ---------------------------------------------------------------------------
__global__ __launch_bounds__(512, 2)
void reduce_kv(const __hip_bfloat16* __restrict__ qkv, __hip_bfloat16* __restrict__ kv2t,
               float* __restrict__ vmeanb) {
    __shared__ __align__(16) __hip_bfloat16 T[512 * 64];   // 64 KB
    const int bt = blockIdx.x;
    const int tid = threadIdx.x;
    const int lane = tid & 63;
    const int h = tid >> 6;
    const int l15 = lane & 15, lq = lane >> 4;
    const int co = tid >> 3;
    const int np3 = tid & 7;
    const size_t rowbase = (size_t)bt * N_;

    union S8 { short8 v; unsigned short u[8]; };
    const short8 zero8 = {0, 0, 0, 0, 0, 0, 0, 0};

    auto issue_loads = [&](int n0, S8* Aq, S8* Bq) {
        #pragma unroll
        for (int s = 0; s < 4; ++s) {
            int n = n0 + 2 * (np3 + 8 * s);
            Aq[s].v = (n < N_)     ? *(const short8*)&qkv[(rowbase + n) * 768 + 256 + co * 8] : zero8;
            Bq[s].v = (n + 1 < N_) ? *(const short8*)&qkv[(rowbase + n + 1) * 768 + 256 + co * 8] : zero8;
        }
    };
    auto write_lds = [&](S8* Aq, S8* Bq) {
        #pragma unroll
        for (int s = 0; s < 4; ++s) {
            int r = 2 * (np3 + 8 * s);
            int slotbase = ((r >> 3));
            #pragma unroll
            for (int j = 0; j < 8; ++j) {
                int c = co * 8 + j;
                u32 wv = (u32)Aq[s].u[j] | ((u32)Bq[s].u[j] << 16);
                int off = c * 64 + ((slotbase ^ (c & 7)) << 3) + (r & 7);
                *(u32*)&T[off] = wv;
            }
        }
    };

    S8 bufA[4], bufB[4], nxtA[4], nxtB[4];
    issue_loads(0, bufA, bufB);

    f32x4 acc[2][2] = {};
    f32x4 acck[2] = {};
    f32x4 accv[2] = {};
    S8 ones;
    #pragma unroll
    for (int j = 0; j < 8; ++j) ones.u[j] = 0x3F80;   // bf16 1.0

    for (int chunk = 0; chunk < 12; ++chunk) {
        if (chunk < 11) issue_loads((chunk + 1) * 64, nxtA, nxtB);
        write_lds(bufA, bufB);
        __syncthreads();
        #pragma unroll
        for (int nc = 0; nc < 2; ++nc) {
            short8 af[2], bfr[2];
            int slot = nc * 4 + lq;
            #pragma unroll
            for (int dh = 0; dh < 2; ++dh) {
                int c = h * 32 + dh * 16 + l15;
                af[dh] = *(const short8*)&T[c * 64 + ((slot ^ (c & 7)) << 3)];
            }
            #pragma unroll
            for (int eh = 0; eh < 2; ++eh) {
                int c = 256 + h * 32 + eh * 16 + l15;
                bfr[eh] = *(const short8*)&T[c * 64 + ((slot ^ (c & 7)) << 3)];
            }
            #pragma unroll
            for (int dh = 0; dh < 2; ++dh)
                #pragma unroll
                for (int eh = 0; eh < 2; ++eh)
                    acc[dh][eh] = __builtin_amdgcn_mfma_f32_16x16x32_bf16(af[dh], bfr[eh], acc[dh][eh], 0, 0, 0);
            #pragma unroll
            for (int dh = 0; dh < 2; ++dh)
                acck[dh] = __builtin_amdgcn_mfma_f32_16x16x32_bf16(af[dh], ones.v, acck[dh], 0, 0, 0);
            #pragma unroll
            for (int eh = 0; eh < 2; ++eh)
                accv[eh] = __builtin_amdgcn_mfma_f32_16x16x32_bf16(ones.v, bfr[eh], accv[eh], 0, 0, 0);
        }
        __syncthreads();
        #pragma unroll
        for (int s = 0; s < 4; ++s) { bufA[s] = nxtA[s]; bufB[s] = nxtB[s]; }
    }

    const int bh = bt * 8 + h;
    #pragma unroll
    for (int eh = 0; eh < 2; ++eh) {
        int e = eh * 16 + l15;
        float vme = accv[eh][0] * INVN_;
        #pragma unroll
        for (int dh = 0; dh < 2; ++dh) {
            union { sv4 v; __hip_bfloat16 x[4]; } o;
            #pragma unroll
            for (int j = 0; j < 4; ++j) {
                float km = acck[dh][j] * INVN_;
                float val = acc[dh][eh][j] * (SCALE_ * INVN_) - SCALE_ * km * vme;
                o.x[j] = __float2bfloat16(val);
            }
            *(sv4*)&kv2t[(size_t)bh * 1024 + e * 32 + dh * 16 + lq * 4] = o.v;
        }
        if (lq == 0) vmeanb[bh * 32 + e] = vme;
    }
}

// ---------------------------------------------------------------------------
// fuse_z2 (unchanged)
// ---------------------------------------------------------------------------
__global__ __launch_bounds__(256)
void fuse_z2(const __hip_bfloat16* __restrict__ qkv, const __hip_bfloat16* __restrict__ kv2t,
             const float* __restrict__ vmeanb, const float* __restrict__ rw,
             __hip_bfloat16* __restrict__ Z) {
    __shared__ __align__(16) __hip_bfloat16 attn[64][256];
    __shared__ __align__(16) __hip_bfloat16 kvl[8192];
    int bt = blockIdx.x;
    int n0 = blockIdx.y * 64;
    int rows = (N_ - n0 < 64) ? (N_ - n0) : 64;
    int t = threadIdx.x;
    const size_t rowbase = (size_t)bt * N_;

    {
        const __hip_bfloat16* src = kv2t + (size_t)bt * 8192;
        #pragma unroll
        for (int i = 0; i < 4; ++i) {
            int off = (t + i * 256) * 8;
            *(short8*)&kvl[off] = *(const short8*)&src[off];
        }
    }
    __syncthreads();

    {
        int lane = t & 63, wave = t >> 6;
        int l15 = lane & 15, lq = lane >> 4;
        int r0 = wave * 16;
        int gn = n0 + r0 + l15; if (gn > N_ - 1) gn = N_ - 1;
        const __hip_bfloat16* qrow = qkv + (rowbase + gn) * 768;
        #pragma unroll
        for (int h = 0; h < 8; ++h) {
            short8 af = *(const short8*)&qrow[h * 32 + lq * 8];
            #pragma unroll
            for (int half = 0; half < 2; ++half) {
                short8 bfr = *(const short8*)&kvl[h * 1024 + (half * 16 + l15) * 32 + lq * 8];
                f32x4 acc = {};
                acc = __builtin_amdgcn_mfma_f32_16x16x32_bf16(af, bfr, acc, 0, 0, 0);
                int col = h * 32 + half * 16 + l15;
                float vm = vmeanb[bt * 256 + col];
                #pragma unroll
                for (int j = 0; j < 4; ++j)
                    attn[r0 + lq * 4 + j][col] = __float2bfloat16(acc[j] + vm);
            }
        }
    }
    __syncthreads();

    {
        int tr = t >> 5;
        int c8 = (t & 31) * 8;
        float w0[8], w1_[8], w2_[8];
        #pragma unroll
        for (int u = 0; u < 8; ++u) {
            w0[u]  = rw[bt * 768 + (c8 + u) * 3 + 0];
            w1_[u] = rw[bt * 768 + (c8 + u) * 3 + 1];
            w2_[u] = rw[bt * 768 + (c8 + u) * 3 + 2];
        }
        int rbeg = tr * 8;
        if (rbeg < rows) {
            int rend = rbeg + 8; if (rend > rows) rend = rows;
            union U8 { short8 v; __hip_bfloat16 h[8]; };
            auto loadv = [&](int gn, float* dst) {
                if (gn >= 0 && gn < N_) {
                    U8 u; u.v = *(const short8*)&qkv[(rowbase + gn) * 768 + 512 + c8];
                    #pragma unroll
                    for (int uu = 0; uu < 8; ++uu) dst[uu] = __bfloat162float(u.h[uu]);
                } else {
                    #pragma unroll
                    for (int uu = 0; uu < 8; ++uu) dst[uu] = 0.0f;
                }
            };
            float vprev[8], vcur[8], vnext[8];
            loadv(n0 + rbeg - 1, vprev);
            loadv(n0 + rbeg, vcur);
            for (int r = rbeg; r < rend; ++r) {
                int gn = n0 + r;
                loadv(gn + 1, vnext);
                U8 at; at.v = *(const short8*)&attn[r][c8];
                U8 zv;
                #pragma unroll
                for (int u = 0; u < 8; ++u) {
                    float s = __bfloat162float(at.h[u]) + w0[u] * vprev[u]
                              + w1_[u] * vcur[u] + w2_[u] * vnext[u];
                    zv.h[u] = __float2bfloat16(s);
                }
                *(short8*)&Z[(rowbase + gn) * 256 + c8] = zv.v;
                #pragma unroll
                for (int u = 0; u < 8; ++u) { vprev[u] = vcur[u]; vcur[u] = vnext[u]; }
            }
        }
    }
}

// ---------------------------------------------------------------------------
extern "C" void kernel_launch(void* const* d_in, const int* in_sizes, int n_in,
                              void* d_out, int out_size, void* d_ws, size_t ws_size,
                              hipStream_t stream) {
    (void)in_sizes; (void)n_in; (void)out_size; (void)ws_size;
    const float* x  = (const float*)d_in[0];
    const float* Wq = (const float*)d_in[1];  const float* bq = (const float*)d_in[2];
    const float* Wk = (const float*)d_in[3];  const float* bk = (const float*)d_in[4];
    const float* Wv = (const float*)d_in[5];  const float* bv = (const float*)d_in[6];
    const float* Wo = (const float*)d_in[7];  const float* bo = (const float*)d_in[8];
    const float* w1 = (const float*)d_in[9];  const float* b1 = (const float*)d_in[10];
    const float* w2 = (const float*)d_in[11]; const float* b2 = (const float*)d_in[12];
    float* out = (float*)d_out;

    char* ws = (char*)d_ws;
    size_t off = 0;
    auto take = [&](size_t bytes) -> char* {
        char* p = ws + off;
        off = (off + bytes + 255) & ~(size_t)255;
        return p;
    };

    __hip_bfloat16* qkv   = (__hip_bfloat16*)take((size_t)MROWS * 768 * 2);
    __hip_bfloat16* Zbuf  = (__hip_bfloat16*)take((size_t)MROWS * 256 * 2);
    __hip_bfloat16* wqkv  = (__hip_bfloat16*)take(768 * 256 * 2);
    __hip_bfloat16* wo    = (__hip_bfloat16*)take(256 * 256 * 2);
    float* bqkv   = (float*)take(768 * 4);
    float* msum   = (float*)take(384 * 256 * 4);
    float* rw     = (float*)take(384 * 768 * 4);
    __hip_bfloat16* kv2t = (__hip_bfloat16*)take((size_t)384 * 8192 * 2);
    float* vmeanb = (float*)take(384 * 256 * 4);

    hipMemsetAsync(msum, 0, 384 * 256 * 4, stream);

    prep_weights<<<768, 256, 0, stream>>>(Wq, bq, Wk, bk, Wv, bv, Wo, wqkv, bqkv, wo);
    // Fused: x f32 -> (convert+msum) -> QKV projection, bias fused
    gemm_xfused<<<1536, 256, 0, stream>>>(x, wqkv, bqkv, qkv, msum);
    mlp_rw<<<384, 256, 0, stream>>>(msum, w1, b1, w2, b2, rw);
    reduce_kv<<<384, 512, 0, stream>>>(qkv, kv2t, vmeanb);
    fuse_z2<<<dim3(384, 12), 256, 0, stream>>>(qkv, kv2t, vmeanb, rw, Zbuf);
    // Output projection: [274944,256] x [256,256]^T -> f32 out, bias fused
    gemm_out<<<512, 256, 0, stream>>>(Zbuf, wo, bo, out);
}

// Round 15
// 542.524 us; speedup vs baseline: 1.4329x; 1.4329x over previous
//
#include <hip/hip_runtime.h>
#include <hip/hip_bf16.h>
#include <math.h>

typedef __attribute__((ext_vector_type(8))) short short8;
typedef __attribute__((ext_vector_type(4))) short sv4;
typedef __attribute__((ext_vector_type(4))) float f32x4;
typedef unsigned int u32;

#define BT_ 384
#define N_ 716
#define C_ 256
#define H_ 8
#define D_ 32
#define MROWS (BT_ * N_)   /* 274944 */
#define NT_ (MROWS / 64)   /* 4296 row-tiles of 64 */
#define SCALE_ 0.17677669529663687f  /* 32^-0.5 */
#define INVN_ (1.0f / 716.0f)

__device__ __forceinline__ void gload_lds16(const void* g, void* l) {
    __builtin_amdgcn_global_load_lds(
        (const __attribute__((address_space(1))) u32*)g,
        (__attribute__((address_space(3))) u32*)l, 16, 0, 0);
}

// ---------------------------------------------------------------------------
// Assemble bf16 weight matrices + fused qkv bias. Wqkv_b[768][256], Wo_b[256][256]
// ---------------------------------------------------------------------------
__global__ void prep_weights(const float* __restrict__ Wq, const float* __restrict__ bq,
                             const float* __restrict__ Wk, const float* __restrict__ bk,
                             const float* __restrict__ Wv, const float* __restrict__ bv,
                             const float* __restrict__ Wo,
                             __hip_bfloat16* __restrict__ wqkv, float* __restrict__ bqkv,
                             __hip_bfloat16* __restrict__ wo) {
    int idx = blockIdx.x * 256 + threadIdx.x;
    if (idx < 768 * 256) {
        int o = idx >> 8, c = idx & 255;
        const float* W = (o < 256) ? Wq : ((o < 512) ? Wk : Wv);
        int oo = o & 255;
        wqkv[idx] = __float2bfloat16(W[oo * 256 + c]);
    }
    if (idx < 256 * 256) wo[idx] = __float2bfloat16(Wo[idx]);
    if (idx < 768) bqkv[idx] = (idx < 256) ? bq[idx] : ((idx < 512) ? bk[idx - 256] : bv[idx - 512]);
}

// ---------------------------------------------------------------------------
// x fp32 -> bf16 (vectorized float4/short4), plus per-(bt,channel) col sums
// grid (384, 4), block 256.
// ---------------------------------------------------------------------------
__global__ __launch_bounds__(256)
void convert_x(const float* __restrict__ x, __hip_bfloat16* __restrict__ xb,
               float* __restrict__ msum) {
    int bt = blockIdx.x, chunk = blockIdx.y;
    int t = threadIdx.x;
    int c4 = (t & 63) * 4;
    int r0 = t >> 6;
    size_t base = ((size_t)bt * N_ + (size_t)chunk * 179) * C_;
    float s0 = 0.f, s1 = 0.f, s2 = 0.f, s3 = 0.f;
    for (int r = r0; r < 179; r += 4) {
        float4 f = *(const float4*)&x[base + (size_t)r * C_ + c4];
        union { sv4 v; __hip_bfloat16 h[4]; } u;
        u.h[0] = __float2bfloat16(f.x);
        u.h[1] = __float2bfloat16(f.y);
        u.h[2] = __float2bfloat16(f.z);
        u.h[3] = __float2bfloat16(f.w);
        *(sv4*)&xb[base + (size_t)r * C_ + c4] = u.v;
        s0 += f.x; s1 += f.y; s2 += f.z; s3 += f.w;
    }
    atomicAdd(&msum[bt * C_ + c4 + 0], s0);
    atomicAdd(&msum[bt * C_ + c4 + 1], s1);
    atomicAdd(&msum[bt * C_ + c4 + 2], s2);
    atomicAdd(&msum[bt * C_ + c4 + 3], s3);
}

// ---------------------------------------------------------------------------
// Grouped 2-layer MLP -> per-channel 3-tap conv weights rw[bt][768]
// ---------------------------------------------------------------------------
__global__ __launch_bounds__(256)
void mlp_rw(const float* __restrict__ msum, const float* __restrict__ w1,
            const float* __restrict__ b1, const float* __restrict__ w2,
            const float* __restrict__ b2, float* __restrict__ rw) {
    int bt = blockIdx.x;
    int t = threadIdx.x;
    __shared__ float m_l[256];
    __shared__ float h1_l[256];
    m_l[t] = msum[bt * 256 + t] * INVN_;
    __syncthreads();
    int g = t >> 5;
    float a = b1[t];
    #pragma unroll
    for (int i = 0; i < 32; ++i) a += m_l[g * 32 + i] * w1[t * 32 + i];
    h1_l[t] = 0.5f * a * (1.0f + erff(a * 0.70710678118654752f));
    __syncthreads();
    for (int o = t; o < 768; o += 256) {
        int gg = o / 96;
        float s = b2[o];
        #pragma unroll
        for (int i = 0; i < 32; ++i) s += h1_l[gg * 32 + i] * w2[o * 32 + i];
        rw[bt * 768 + o] = s;
    }
}

// ---------------------------------------------------------------------------
// Persistent B-resident GEMM v2 (R9, best measured): 4 waves, wave tile
// 64x32, B in regs (bf[2][8]=64 VGPR), XCD-aware 1D grid (all col-blocks of
// a stripe on one XCD), A double-buffered 64KB LDS (XOR swizzle, gload_lds),
// stage-before-compute, LDS-coalesced epilogue, counted end-of-tile vmcnt.
// Hardening vs R9: bf16 path waits vmcnt(2) (drains all 8 stage loads;
// R9's vmcnt(4) left 2 loads unconfirmed — latent race).
// grid GRIDX*256 (1D), block 256.
// ---------------------------------------------------------------------------
template<int NCOLS, int GRIDX, bool OUT_BF16>
__global__ __launch_bounds__(256, 2)
void gemm_persist(const __hip_bfloat16* __restrict__ A, const __hip_bfloat16* __restrict__ Bm,
                  const float* __restrict__ bias, void* __restrict__ outp) {
    __shared__ __align__(16) __hip_bfloat16 As[2][64 * 256];   // 2 x 32KB
    const int L = blockIdx.x;
    const int xcd = L & 7, w = L >> 3;
    const int cb = w % GRIDX;
    const int ib = xcd * 32 + w / GRIDX;    // stripe 0..255; all cb of ib share xcd
    const int tid = threadIdx.x;
    const int lane = tid & 63;
    const int wave = tid >> 6;       // 0..3
    const int wn = wave;             // 32-col quarter
    const int colBase = cb * 128;
    const int l15 = lane & 15, lq = lane >> 4;
    const int lrow2 = lane >> 5;     // 0/1
    const int p = lane & 31;

    auto stageA = [&](int rt, int buf) {
        #pragma unroll
        for (int i = 0; i < 8; ++i) {
            int r = wave * 16 + 2 * i + lrow2;
            const __hip_bfloat16* g = A + ((size_t)rt * 64 + r) * 256 + ((p ^ (r & 7)) * 8);
            gload_lds16(g, &As[buf][(wave * 16 + 2 * i) * 256]);
        }
    };

    stageA(ib, 0);

    // B fragments in registers: 2 x 8 x short8 = 64 VGPR (loop-invariant)
    short8 bf[2][8];
    #pragma unroll
    for (int n = 0; n < 2; ++n)
        #pragma unroll
        for (int ks = 0; ks < 8; ++ks)
            bf[n][ks] = *(const short8*)&Bm[(size_t)(colBase + wn * 32 + n * 16 + l15) * 256 + ks * 32 + lq * 8];
    float biasr[2];
    #pragma unroll
    for (int n = 0; n < 2; ++n)
        biasr[n] = bias[colBase + wn * 32 + n * 16 + l15];

    asm volatile("s_waitcnt vmcnt(0)" ::: "memory");
    __builtin_amdgcn_s_barrier();

    int buf = 0;
    for (int rt = ib; rt < NT_; rt += 256) {
        int rtn = rt + 256;
        if (rtn < NT_) stageA(rtn, buf ^ 1);

        // compute 64x128: wave computes rows 0..63 x cols wn*32..+32
        f32x4 acc[4][2] = {};
        #pragma unroll
        for (int ks = 0; ks < 8; ++ks) {
            short8 af[4];
            #pragma unroll
            for (int m = 0; m < 4; ++m) {
                int row = m * 16 + l15;
                af[m] = *(const short8*)&As[buf][row * 256 + (((ks * 4 + lq) ^ (row & 7)) * 8)];
            }
            #pragma unroll
            for (int m = 0; m < 4; ++m)
                #pragma unroll
                for (int n = 0; n < 2; ++n)
                    acc[m][n] = __builtin_amdgcn_mfma_f32_16x16x32_bf16(af[m], bf[n][ks], acc[m][n], 0, 0, 0);
        }
        asm volatile("s_waitcnt lgkmcnt(0)" ::: "memory");
        __builtin_amdgcn_s_barrier();          // all waves done reading As[buf]

        if constexpr (OUT_BF16) {
            __hip_bfloat16* Cs = &As[buf][0];  // [64][136], 17.4KB
            #pragma unroll
            for (int m = 0; m < 4; ++m)
                #pragma unroll
                for (int n = 0; n < 2; ++n) {
                    int col = wn * 32 + n * 16 + l15;
                    #pragma unroll
                    for (int j = 0; j < 4; ++j)
                        Cs[(m * 16 + lq * 4 + j) * 136 + col] =
                            __float2bfloat16(acc[m][n][j] + biasr[n]);
                }
            asm volatile("s_waitcnt lgkmcnt(0)" ::: "memory");
            __builtin_amdgcn_s_barrier();
            int row = tid >> 2, cq = tid & 3;
            __hip_bfloat16* og = (__hip_bfloat16*)outp + ((size_t)rt * 64 + row) * NCOLS + colBase;
            #pragma unroll
            for (int i = 0; i < 4; ++i) {
                int col = cq * 8 + i * 32;
                *(short8*)&og[col] = *(const short8*)&Cs[row * 136 + col];
            }
            // outstanding: 8 stage loads (oldest) + 2 stores. vmcnt(2)
            // drains ALL stage loads; stores stay in flight.
            asm volatile("s_waitcnt vmcnt(2) lgkmcnt(0)" ::: "memory");
            __builtin_amdgcn_s_barrier();
        } else {
            float* Cs = (float*)&As[buf][0];   // [32][132] per pass, 16.9KB
            #pragma unroll
            for (int pp = 0; pp < 2; ++pp) {
                #pragma unroll
                for (int mm = 0; mm < 2; ++mm) {
                    int m = 2 * pp + mm;
                    #pragma unroll
                    for (int n = 0; n < 2; ++n) {
                        int col = wn * 32 + n * 16 + l15;
                        #pragma unroll
                        for (int j = 0; j < 4; ++j)
                            Cs[(mm * 16 + lq * 4 + j) * 132 + col] = acc[m][n][j] + biasr[n];
                    }
                }
                asm volatile("s_waitcnt lgkmcnt(0)" ::: "memory");
                __builtin_amdgcn_s_barrier();
                int row = tid >> 3, k = tid & 7;
                float* og = (float*)outp + ((size_t)rt * 64 + pp * 32 + row) * NCOLS + colBase;
                #pragma unroll
                for (int i = 0; i < 4; ++i) {
                    int col = k * 4 + i * 32;
                    *(float4*)&og[col] = *(const float4*)&Cs[row * 132 + col];
                }
                asm volatile("s_waitcnt lgkmcnt(0)" ::: "memory");
                __builtin_amdgcn_s_barrier();
            }
            // outstanding: 8 stage loads (oldest) + 8 stores. vmcnt(4)
            // drains all loads + 4 stores; 4 stores stay in flight.
            asm volatile("s_waitcnt vmcnt(4) lgkmcnt(0)" ::: "memory");
            __builtin_amdgcn_s_barrier();
        }
        buf ^= 1;
    }
}

// ---------------------------------------------------------------------------
// MFMA reduce_kv (R8): one block per bt, 8 waves = 8 heads.
// ---------------------------------------------------------------------------
__global__ __launch_bounds__(512, 2)
void reduce_kv(const __hip_bfloat16* __restrict__ qkv, __hip_bfloat16* __restrict__ kv2t,
               float* __restrict__ vmeanb) {
    __shared__ __align__(16) __hip_bfloat16 T[512 * 64];   // 64 KB
    const int bt = blockIdx.x;
    const int tid = threadIdx.x;
    const int lane = tid & 63;
    const int h = tid >> 6;
    const int l15 = lane & 15, lq = lane >> 4;
    const int co = tid >> 3;
    const int np3 = tid & 7;
    const size_t rowbase = (size_t)bt * N_;

    union S8 { short8 v; unsigned short u[8]; };
    const short8 zero8 = {0, 0, 0, 0, 0, 0, 0, 0};

    auto issue_loads = [&](int n0, S8* Aq, S8* Bq) {
        #pragma unroll
        for (int s = 0; s < 4; ++s) {
            int n = n0 + 2 * (np3 + 8 * s);
            Aq[s].v = (n < N_)     ? *(const short8*)&qkv[(rowbase + n) * 768 + 256 + co * 8] : zero8;
            Bq[s].v = (n + 1 < N_) ? *(const short8*)&qkv[(rowbase + n + 1) * 768 + 256 + co * 8] : zero8;
        }
    };
    auto write_lds = [&](S8* Aq, S8* Bq) {
        #pragma unroll
        for (int s = 0; s < 4; ++s) {
            int r = 2 * (np3 + 8 * s);
            int slotbase = ((r >> 3));
            #pragma unroll
            for (int j = 0; j < 8; ++j) {
                int c = co * 8 + j;
                u32 wv = (u32)Aq[s].u[j] | ((u32)Bq[s].u[j] << 16);
                int off = c * 64 + ((slotbase ^ (c & 7)) << 3) + (r & 7);
                *(u32*)&T[off] = wv;
            }
        }
    };

    S8 bufA[4], bufB[4], nxtA[4], nxtB[4];
    issue_loads(0, bufA, bufB);

    f32x4 acc[2][2] = {};
    f32x4 acck[2] = {};
    f32x4 accv[2] = {};
    S8 ones;
    #pragma unroll
    for (int j = 0; j < 8; ++j) ones.u[j] = 0x3F80;   // bf16 1.0

    for (int chunk = 0; chunk < 12; ++chunk) {
        if (chunk < 11) issue_loads((chunk + 1) * 64, nxtA, nxtB);
        write_lds(bufA, bufB);
        __syncthreads();
        #pragma unroll
        for (int nc = 0; nc < 2; ++nc) {
            short8 af[2], bfr[2];
            int slot = nc * 4 + lq;
            #pragma unroll
            for (int dh = 0; dh < 2; ++dh) {
                int c = h * 32 + dh * 16 + l15;
                af[dh] = *(const short8*)&T[c * 64 + ((slot ^ (c & 7)) << 3)];
            }
            #pragma unroll
            for (int eh = 0; eh < 2; ++eh) {
                int c = 256 + h * 32 + eh * 16 + l15;
                bfr[eh] = *(const short8*)&T[c * 64 + ((slot ^ (c & 7)) << 3)];
            }
            #pragma unroll
            for (int dh = 0; dh < 2; ++dh)
                #pragma unroll
                for (int eh = 0; eh < 2; ++eh)
                    acc[dh][eh] = __builtin_amdgcn_mfma_f32_16x16x32_bf16(af[dh], bfr[eh], acc[dh][eh], 0, 0, 0);
            #pragma unroll
            for (int dh = 0; dh < 2; ++dh)
                acck[dh] = __builtin_amdgcn_mfma_f32_16x16x32_bf16(af[dh], ones.v, acck[dh], 0, 0, 0);
            #pragma unroll
            for (int eh = 0; eh < 2; ++eh)
                accv[eh] = __builtin_amdgcn_mfma_f32_16x16x32_bf16(ones.v, bfr[eh], accv[eh], 0, 0, 0);
        }
        __syncthreads();
        #pragma unroll
        for (int s = 0; s < 4; ++s) { bufA[s] = nxtA[s]; bufB[s] = nxtB[s]; }
    }

    const int bh = bt * 8 + h;
    #pragma unroll
    for (int eh = 0; eh < 2; ++eh) {
        int e = eh * 16 + l15;
        float vme = accv[eh][0] * INVN_;
        #pragma unroll
        for (int dh = 0; dh < 2; ++dh) {
            union { sv4 v; __hip_bfloat16 x[4]; } o;
            #pragma unroll
            for (int j = 0; j < 4; ++j) {
                float km = acck[dh][j] * INVN_;
                float val = acc[dh][eh][j] * (SCALE_ * INVN_) - SCALE_ * km * vme;
                o.x[j] = __float2bfloat16(val);
            }
            *(sv4*)&kv2t[(size_t)bh * 1024 + e * 32 + dh * 16 + lq * 4] = o.v;
        }
        if (lq == 0) vmeanb[bh * 32 + e] = vme;
    }
}

// ---------------------------------------------------------------------------
// fuse_z2 (R6-vectorized, unchanged)
// ---------------------------------------------------------------------------
__global__ __launch_bounds__(256)
void fuse_z2(const __hip_bfloat16* __restrict__ qkv, const __hip_bfloat16* __restrict__ kv2t,
             const float* __restrict__ vmeanb, const float* __restrict__ rw,
             __hip_bfloat16* __restrict__ Z) {
    __shared__ __align__(16) __hip_bfloat16 attn[64][256];
    __shared__ __align__(16) __hip_bfloat16 kvl[8192];
    int bt = blockIdx.x;
    int n0 = blockIdx.y * 64;
    int rows = (N_ - n0 < 64) ? (N_ - n0) : 64;
    int t = threadIdx.x;
    const size_t rowbase = (size_t)bt * N_;

    {
        const __hip_bfloat16* src = kv2t + (size_t)bt * 8192;
        #pragma unroll
        for (int i = 0; i < 4; ++i) {
            int off = (t + i * 256) * 8;
            *(short8*)&kvl[off] = *(const short8*)&src[off];
        }
    }
    __syncthreads();

    {
        int lane = t & 63, wave = t >> 6;
        int l15 = lane & 15, lq = lane >> 4;
        int r0 = wave * 16;
        int gn = n0 + r0 + l15; if (gn > N_ - 1) gn = N_ - 1;
        const __hip_bfloat16* qrow = qkv + (rowbase + gn) * 768;
        #pragma unroll
        for (int h = 0; h < 8; ++h) {
            short8 af = *(const short8*)&qrow[h * 32 + lq * 8];
            #pragma unroll
            for (int half = 0; half < 2; ++half) {
                short8 bfr = *(const short8*)&kvl[h * 1024 + (half * 16 + l15) * 32 + lq * 8];
                f32x4 acc = {};
                acc = __builtin_amdgcn_mfma_f32_16x16x32_bf16(af, bfr, acc, 0, 0, 0);
                int col = h * 32 + half * 16 + l15;
                float vm = vmeanb[bt * 256 + col];
                #pragma unroll
                for (int j = 0; j < 4; ++j)
                    attn[r0 + lq * 4 + j][col] = __float2bfloat16(acc[j] + vm);
            }
        }
    }
    __syncthreads();

    {
        int tr = t >> 5;
        int c8 = (t & 31) * 8;
        float w0[8], w1_[8], w2_[8];
        #pragma unroll
        for (int u = 0; u < 8; ++u) {
            w0[u]  = rw[bt * 768 + (c8 + u) * 3 + 0];
            w1_[u] = rw[bt * 768 + (c8 + u) * 3 + 1];
            w2_[u] = rw[bt * 768 + (c8 + u) * 3 + 2];
        }
        int rbeg = tr * 8;
        if (rbeg < rows) {
            int rend = rbeg + 8; if (rend > rows) rend = rows;
            union U8 { short8 v; __hip_bfloat16 h[8]; };
            auto loadv = [&](int gn, float* dst) {
                if (gn >= 0 && gn < N_) {
                    U8 u; u.v = *(const short8*)&qkv[(rowbase + gn) * 768 + 512 + c8];
                    #pragma unroll
                    for (int uu = 0; uu < 8; ++uu) dst[uu] = __bfloat162float(u.h[uu]);
                } else {
                    #pragma unroll
                    for (int uu = 0; uu < 8; ++uu) dst[uu] = 0.0f;
                }
            };
            float vprev[8], vcur[8], vnext[8];
            loadv(n0 + rbeg - 1, vprev);
            loadv(n0 + rbeg, vcur);
            for (int r = rbeg; r < rend; ++r) {
                int gn = n0 + r;
                loadv(gn + 1, vnext);
                U8 at; at.v = *(const short8*)&attn[r][c8];
                U8 zv;
                #pragma unroll
                for (int u = 0; u < 8; ++u) {
                    float s = __bfloat162float(at.h[u]) + w0[u] * vprev[u]
                              + w1_[u] * vcur[u] + w2_[u] * vnext[u];
                    zv.h[u] = __float2bfloat16(s);
                }
                *(short8*)&Z[(rowbase + gn) * 256 + c8] = zv.v;
                #pragma unroll
                for (int u = 0; u < 8; ++u) { vprev[u] = vcur[u]; vcur[u] = vnext[u]; }
            }
        }
    }
}

// ---------------------------------------------------------------------------
extern "C" void kernel_launch(void* const* d_in, const int* in_sizes, int n_in,
                              void* d_out, int out_size, void* d_ws, size_t ws_size,
                              hipStream_t stream) {
    (void)in_sizes; (void)n_in; (void)out_size; (void)ws_size;
    const float* x  = (const float*)d_in[0];
    const float* Wq = (const float*)d_in[1];  const float* bq = (const float*)d_in[2];
    const float* Wk = (const float*)d_in[3];  const float* bk = (const float*)d_in[4];
    const float* Wv = (const float*)d_in[5];  const float* bv = (const float*)d_in[6];
    const float* Wo = (const float*)d_in[7];  const float* bo = (const float*)d_in[8];
    const float* w1 = (const float*)d_in[9];  const float* b1 = (const float*)d_in[10];
    const float* w2 = (const float*)d_in[11]; const float* b2 = (const float*)d_in[12];
    float* out = (float*)d_out;

    char* ws = (char*)d_ws;
    size_t off = 0;
    auto take = [&](size_t bytes) -> char* {
        char* p = ws + off;
        off = (off + bytes + 255) & ~(size_t)255;
        return p;
    };

    __hip_bfloat16* qkv   = (__hip_bfloat16*)take((size_t)MROWS * 768 * 2);
    __hip_bfloat16* xb    = (__hip_bfloat16*)take((size_t)MROWS * 256 * 2);
    __hip_bfloat16* Zbuf  = xb;  // alias: xb dead after gemm_qkv, reused for Z
    __hip_bfloat16* wqkv  = (__hip_bfloat16*)take(768 * 256 * 2);
    __hip_bfloat16* wo    = (__hip_bfloat16*)take(256 * 256 * 2);
    float* bqkv   = (float*)take(768 * 4);
    float* msum   = (float*)take(384 * 256 * 4);
    float* rw     = (float*)take(384 * 768 * 4);
    __hip_bfloat16* kv2t = (__hip_bfloat16*)take((size_t)384 * 8192 * 2);
    float* vmeanb = (float*)take(384 * 256 * 4);

    hipMemsetAsync(msum, 0, 384 * 256 * 4, stream);

    prep_weights<<<768, 256, 0, stream>>>(Wq, bq, Wk, bk, Wv, bv, Wo, wqkv, bqkv, wo);
    convert_x<<<dim3(384, 4), 256, 0, stream>>>(x, xb, msum);
    mlp_rw<<<384, 256, 0, stream>>>(msum, w1, b1, w2, b2, rw);
    // QKV projection: [274944,256] x [768,256]^T -> bf16 qkv, bias fused
    gemm_persist<768, 6, true><<<1536, 256, 0, stream>>>(xb, wqkv, bqkv, qkv);
    reduce_kv<<<384, 512, 0, stream>>>(qkv, kv2t, vmeanb);
    fuse_z2<<<dim3(384, 12), 256, 0, stream>>>(qkv, kv2t, vmeanb, rw, Zbuf);
    // Output projection: [274944,256] x [256,256]^T -> f32 out, bias fused
    gemm_persist<256, 2, false><<<512, 256, 0, stream>>>(Zbuf, wo, bo, out);
}